// Round 12
// baseline (281.101 us; speedup 1.0000x reference)
//
#include <hip/hip_runtime.h>

typedef _Float16 f16;
typedef __attribute__((ext_vector_type(8))) _Float16 half8;
typedef __attribute__((ext_vector_type(4))) _Float16 half4;
typedef __attribute__((ext_vector_type(2))) _Float16 half2v;
typedef __attribute__((ext_vector_type(4))) float f32x4;

#define S_LEN 4096
#define HID   768
#define NH    12
#define HD    64

#define EXP2(x) __builtin_amdgcn_exp2f(x)
#define PKRTZ(a, b) __builtin_bit_cast(half2v, __builtin_amdgcn_cvt_pkrtz((a), (b)))

// ---------------- convert hidden_states f32 -> f16 ----------------
__global__ __launch_bounds__(256) void k_convert_x(const float* __restrict__ x,
                                                   f16* __restrict__ xb) {
  int i = blockIdx.x * 256 + threadIdx.x;
  float4 v = ((const float4*)x)[i];
  half4 h;
  h[0] = (f16)v.x; h[1] = (f16)v.y; h[2] = (f16)v.z; h[3] = (f16)v.w;
  *(half4*)&xb[(size_t)i * 4] = h;
}

// ---------------- mask * log2(e) precompute ----------------
__global__ __launch_bounds__(256) void k_maskcvt(const float* __restrict__ m,
                                                 float* __restrict__ m2) {
  int i = blockIdx.x * 256 + threadIdx.x;
  const float LOG2E = 1.4426950408889634f;
  float4 v = ((const float4*)m)[i];
  ((float4*)m2)[i] = make_float4(v.x * LOG2E, v.y * LOG2E, v.z * LOG2E, v.w * LOG2E);
}

// ---------------- transpose W [K,N] -> wt [N,K], f32 -> f16 ----------------
__global__ __launch_bounds__(256) void k_transw(const float* __restrict__ Wq,
                                                const float* __restrict__ Wk,
                                                const float* __restrict__ Wv,
                                                f16* __restrict__ wtb) {
  __shared__ float tile[32][33];
  const float* W = (blockIdx.z == 0) ? Wq : (blockIdx.z == 1 ? Wk : Wv);
  f16* wt = wtb + (size_t)blockIdx.z * HID * HID;
  int k0 = blockIdx.y * 32, n0 = blockIdx.x * 32;
  int tx = threadIdx.x, ty = threadIdx.y;
  #pragma unroll
  for (int j = ty; j < 32; j += 8)
    tile[j][tx] = W[(size_t)(k0 + j) * HID + n0 + tx];
  __syncthreads();
  #pragma unroll
  for (int j = ty; j < 32; j += 8)
    wt[(size_t)(n0 + j) * HID + k0 + tx] = (f16)tile[tx][j];
}

// ---------------- QKV projection GEMM (m97-style, 128x128 tile) ----------------
__global__ __launch_bounds__(256) void k_gemm_qkv(const f16* __restrict__ xb,
                                                  const f16* __restrict__ wtb,
                                                  const float* __restrict__ bq,
                                                  const float* __restrict__ bk,
                                                  const float* __restrict__ bv,
                                                  f16* __restrict__ qo,
                                                  f16* __restrict__ ko,
                                                  f16* __restrict__ vto) {
  __shared__ __align__(16) f16 As[128 * 32];
  __shared__ __align__(16) f16 Bs[128 * 32];
  const int z = blockIdx.z;
  const f16* wt = wtb + (size_t)z * HID * HID;
  const float* bias = (z == 0) ? bq : (z == 1 ? bk : bv);
  const int brow = blockIdx.y * 128;
  const int bcol = blockIdx.x * 128;
  const int tid = threadIdx.x, wid = tid >> 6, lane = tid & 63;
  const int wr = wid >> 1, wc = wid & 1;
  const int lrow = lane & 15, lk8 = (lane >> 4) * 8;
  const int srow = lane >> 2;
  const int scol = (lane & 3) * 8;

  f32x4 acc[4][4] = {};

  for (int kt = 0; kt < HID; kt += 32) {
    #pragma unroll
    for (int r = 0; r < 2; r++) {
      int row = (wid * 2 + r) * 16 + srow;
      const f16* ga = xb + (size_t)(brow + row) * HID + kt + scol;
      const f16* gb = wt + (size_t)(bcol + row) * HID + kt + scol;
      __builtin_amdgcn_global_load_lds(
          (const __attribute__((address_space(1))) void*)ga,
          (__attribute__((address_space(3))) void*)(As + (wid * 2 + r) * 512),
          16, 0, 0);
      __builtin_amdgcn_global_load_lds(
          (const __attribute__((address_space(1))) void*)gb,
          (__attribute__((address_space(3))) void*)(Bs + (wid * 2 + r) * 512),
          16, 0, 0);
    }
    __syncthreads();

    half8 a[4], b[4];
    #pragma unroll
    for (int m = 0; m < 4; m++)
      a[m] = *(const half8*)&As[(wr * 64 + m * 16 + lrow) * 32 + lk8];
    #pragma unroll
    for (int n = 0; n < 4; n++)
      b[n] = *(const half8*)&Bs[(wc * 64 + n * 16 + lrow) * 32 + lk8];
    #pragma unroll
    for (int m = 0; m < 4; m++)
      #pragma unroll
      for (int n = 0; n < 4; n++)
        acc[m][n] = __builtin_amdgcn_mfma_f32_16x16x32_f16(a[m], b[n], acc[m][n], 0, 0, 0);
    __syncthreads();
  }

  #pragma unroll
  for (int m = 0; m < 4; m++) {
    int row0 = brow + wr * 64 + m * 16 + (lane >> 4) * 4;
    #pragma unroll
    for (int n = 0; n < 4; n++) {
      int col = bcol + wc * 64 + n * 16 + lrow;
      float bsv = bias[col];
      int h = col >> 6, d = col & 63;
      #pragma unroll
      for (int i = 0; i < 4; i++) {
        f16 v = (f16)(acc[m][n][i] + bsv);
        int r2 = row0 + i;
        if (z == 2)      vto[(size_t)(h * HD + d) * S_LEN + r2] = v;
        else if (z == 1) ko[((size_t)h * S_LEN + r2) * HD + d] = v;
        else             qo[((size_t)h * S_LEN + r2) * HD + d] = v;
      }
    }
  }
}

// ---------------- flash attention (K-direct, V-LDS, split-KV) ------------------
// grid (64 q-blocks, 12 heads, split), 256 thr = 4 waves, wave owns 16 q rows.
// K fragments read DIRECT from global (coalesced: 16 consecutive 128B rows per
// 16-lane group; L2-resident) — no K LDS. V staged to LDS (dbuf, gload_lds w=16,
// XOR-swizzled source; V^T-direct is transaction-bound per R9). LDS 25.6 KB ->
// 6 blocks/CU; grid 1536 -> up to 6 independent block-streams/CU (R10 had 3).
// Swapped QK^T, per-lane softmax stats, defer-max T13, P via per-wave LDS.
__global__ __launch_bounds__(256) void k_attn(const f16* __restrict__ qb,
                                              const f16* __restrict__ kb,
                                              const f16* __restrict__ vt,
                                              const float* __restrict__ mask2,
                                              float* __restrict__ dsto,
                                              float* __restrict__ ml,
                                              int nkt, int direct) {
  __shared__ __align__(16) f16 Vs[2][64 * 64];   // 8 KB each buf
  __shared__ __align__(16) f16 P[4][16 * 72];    // per-wave P tile, stride 72
  const int h = blockIdx.y, z = blockIdx.z;
  const int tid = threadIdx.x, wid = tid >> 6, lane = tid & 63;
  const int lrow = lane & 15, lk8 = (lane >> 4) * 8, g4 = (lane >> 4) * 4;
  const int grp = lane >> 4;
  const int qrow0 = blockIdx.x * 64 + wid * 16;
  const size_t hqk = (size_t)h * (S_LEN * HD);
  const int kt0 = z * nkt * 64;
  f16* Pw = &P[wid][0];
  const float scale2 = 0.125f * 1.4426950408889634f;

  // V staging geometry: 2 rounds x 256 threads x 16B (8 KB tile)
  const int srow = tid >> 3;
  const int sc   = tid & 7;

  const half8 aq0 = *(const half8*)&qb[hqk + (size_t)(qrow0 + lrow) * HD + lk8];
  const half8 aq1 = *(const half8*)&qb[hqk + (size_t)(qrow0 + lrow) * HD + 32 + lk8];

  f32x4 acc[4] = {};
  float mi = -INFINITY, li = 0.f;

  auto stageV = [&](int buf, int kt) {
    #pragma unroll
    for (int r = 0; r < 2; r++) {
      const int row = r * 32 + srow;
      const int scol = ((sc ^ (row & 7)) << 3);
      const f16* gv = vt + ((size_t)(h * HD + row)) * S_LEN + kt + scol;
      __builtin_amdgcn_global_load_lds(
          (const __attribute__((address_space(1))) void*)gv,
          (__attribute__((address_space(3))) void*)&Vs[buf][r * 2048 + (tid << 3)],
          16, 0, 0);
    }
  };

  stageV(0, kt0);
  __syncthreads();

  for (int it = 0; it < nkt; ++it) {
    const int cur = it & 1;
    const int kt = kt0 + it * 64;
    if (it + 1 < nkt) stageV(cur ^ 1, kt + 64);   // async prefetch next V tile

    // ---- K fragments direct from global (coalesced rows, L2-hit) ----
    half8 b0[4], b1[4];
    #pragma unroll
    for (int nt = 0; nt < 4; nt++) {
      const f16* kp = &kb[hqk + (size_t)(kt + nt * 16 + lrow) * HD + lk8];
      b0[nt] = *(const half8*)kp;
      b1[nt] = *(const half8*)(kp + 32);
    }

    // ---- QK^T swapped: sp[nt][i] = S[k=nt*16+g4+i][q=lrow] ----
    f32x4 sp[4];
    __builtin_amdgcn_s_setprio(1);
    #pragma unroll
    for (int nt = 0; nt < 4; nt++) {
      f32x4 sv = {};
      sv = __builtin_amdgcn_mfma_f32_16x16x32_f16(b0[nt], aq0, sv, 0, 0, 0);
      sv = __builtin_amdgcn_mfma_f32_16x16x32_f16(b1[nt], aq1, sv, 0, 0, 0);
      sp[nt] = sv;
    }
    __builtin_amdgcn_s_setprio(0);

    // ---- scale + pre-scaled mask (log2 domain) ----
    #pragma unroll
    for (int nt = 0; nt < 4; nt++) {
      float4 mk = *(const float4*)&mask2[kt + nt * 16 + g4];
      sp[nt][0] = sp[nt][0] * scale2 + mk.x;
      sp[nt][1] = sp[nt][1] * scale2 + mk.y;
      sp[nt][2] = sp[nt][2] * scale2 + mk.z;
      sp[nt][3] = sp[nt][3] * scale2 + mk.w;
    }
    float mloc = fmaxf(sp[0][0], sp[0][1]);
    mloc = fmaxf(fmaxf(mloc, sp[0][2]), sp[0][3]);
    mloc = fmaxf(fmaxf(mloc, sp[1][0]), sp[1][1]);
    mloc = fmaxf(fmaxf(mloc, sp[1][2]), sp[1][3]);
    mloc = fmaxf(fmaxf(mloc, sp[2][0]), sp[2][1]);
    mloc = fmaxf(fmaxf(mloc, sp[2][2]), sp[2][3]);
    mloc = fmaxf(fmaxf(mloc, sp[3][0]), sp[3][1]);
    mloc = fmaxf(fmaxf(mloc, sp[3][2]), sp[3][3]);
    mloc = fmaxf(mloc, __shfl_xor(mloc, 16, 64));
    mloc = fmaxf(mloc, __shfl_xor(mloc, 32, 64));

    // ---- defer-max (T13, THR=8 -> P <= 256, f16-safe) ----
    float al = 1.f;
    if (!__all(mloc <= mi + 8.f)) {
      const float mn = fmaxf(mi, mloc);
      al = EXP2(mi - mn);
      mi = mn;
      #pragma unroll
      for (int nd = 0; nd < 4; nd++) {
        acc[nd][0] *= al; acc[nd][1] *= al; acc[nd][2] *= al; acc[nd][3] *= al;
      }
    }
    float rs = 0.f;
    #pragma unroll
    for (int nt = 0; nt < 4; nt++)
      #pragma unroll
      for (int i = 0; i < 4; i++) {
        sp[nt][i] = EXP2(sp[nt][i] - mi);
        rs += sp[nt][i];
      }
    rs += __shfl_xor(rs, 16, 64);
    rs += __shfl_xor(rs, 32, 64);
    li = li * al + rs;

    // ---- P -> LDS row-major [q=lrow][k], packed cvt ----
    #pragma unroll
    for (int nt = 0; nt < 4; nt++) {
      half2v lo = PKRTZ(sp[nt][0], sp[nt][1]);
      half2v hi = PKRTZ(sp[nt][2], sp[nt][3]);
      half4 h4;
      h4[0] = lo[0]; h4[1] = lo[1]; h4[2] = hi[0]; h4[3] = hi[1];
      *(half4*)&Pw[lrow * 72 + nt * 16 + g4] = h4;
    }
    // ---- PV from LDS: acc[nd] = O^T[d][q] += V^T[d][k] P^T[k][q] ----
    #pragma unroll
    for (int k2 = 0; k2 < 2; k2++) {
      half8 bp = *(const half8*)&Pw[lrow * 72 + k2 * 32 + lk8];
      __builtin_amdgcn_s_setprio(1);
      #pragma unroll
      for (int nd = 0; nd < 4; nd++) {
        const int vr = nd * 16 + lrow;
        const int xc = (((k2 * 4 + grp) ^ (vr & 7)) << 3);
        half8 av = *(const half8*)&Vs[cur][vr * 64 + xc];
        acc[nd] = __builtin_amdgcn_mfma_f32_16x16x32_f16(av, bp, acc[nd], 0, 0, 0);
      }
      __builtin_amdgcn_s_setprio(0);
    }
    __syncthreads();   // staged V tile landed; release cur buf
  }

  const float inv = (li > 0.f) ? (1.f / li) : 0.f;
  if (direct) {
    #pragma unroll
    for (int nd = 0; nd < 4; nd++) {
      float4 o = make_float4(acc[nd][0] * inv, acc[nd][1] * inv,
                             acc[nd][2] * inv, acc[nd][3] * inv);
      *(float4*)&dsto[(size_t)(qrow0 + lrow) * HID + h * HD + nd * 16 + g4] = o;
    }
  } else {
    const size_t rbase = ((size_t)z * NH + h) * S_LEN + qrow0 + lrow;
    #pragma unroll
    for (int nd = 0; nd < 4; nd++) {
      float4 o = make_float4(acc[nd][0] * inv, acc[nd][1] * inv,
                             acc[nd][2] * inv, acc[nd][3] * inv);
      *(float4*)&dsto[rbase * HD + nd * 16 + g4] = o;
    }
    if (lane < 16) {
      ml[rbase * 2]     = mi;   // log2-domain running max
      ml[rbase * 2 + 1] = li;
    }
  }
}

// ---------------- split-KV combine (log2-domain weights) ----------------
__global__ __launch_bounds__(256) void k_combine(const float* __restrict__ opart,
                                                 const float* __restrict__ ml,
                                                 float* __restrict__ out, int split) {
  const int gid = blockIdx.x * 256 + threadIdx.x;   // NH*S*16 threads
  const int row = gid >> 4;                          // h*S + q
  const int d0 = (gid & 15) << 2;
  const int h = row >> 12, q = row & (S_LEN - 1);
  float M = -INFINITY;
  for (int zz = 0; zz < split; zz++)
    M = fmaxf(M, ml[((size_t)zz * NH * S_LEN + row) * 2]);
  float wsum = 0.f;
  float o0 = 0.f, o1 = 0.f, o2 = 0.f, o3 = 0.f;
  for (int zz = 0; zz < split; zz++) {
    const size_t r = (size_t)zz * NH * S_LEN + row;
    float m = ml[r * 2], l = ml[r * 2 + 1];
    if (l > 0.f) {
      float w = l * EXP2(m - M);
      float4 v = *(const float4*)&opart[r * HD + d0];
      wsum += w;
      o0 += w * v.x; o1 += w * v.y; o2 += w * v.z; o3 += w * v.w;
    }
  }
  const float inv = (wsum > 0.f) ? (1.f / wsum) : 0.f;
  *(float4*)&out[(size_t)q * HID + h * HD + d0] =
      make_float4(o0 * inv, o1 * inv, o2 * inv, o3 * inv);
}

extern "C" void kernel_launch(void* const* d_in, const int* in_sizes, int n_in,
                              void* d_out, int out_size, void* d_ws, size_t ws_size,
                              hipStream_t stream) {
  const float* x    = (const float*)d_in[0];
  const float* mask = (const float*)d_in[1];
  const float* Wq   = (const float*)d_in[2];
  const float* bq   = (const float*)d_in[3];
  const float* Wk   = (const float*)d_in[4];
  const float* bk   = (const float*)d_in[5];
  const float* Wv   = (const float*)d_in[6];
  const float* bv   = (const float*)d_in[7];
  float* out = (float*)d_out;

  char* ws = (char*)d_ws;
  f16* xb  = (f16*)(ws);                       // 4096*768*2       = 6291456 B
  f16* wtb = (f16*)(ws + 6291456);             // 3*768*768*2      = 3538944 B
  f16* qbb = (f16*)(ws + 9830400);             // 12*4096*64*2     = 6291456 B
  f16* kbb = (f16*)(ws + 16121856);            // 6291456 B
  f16* vtb = (f16*)(ws + 22413312);            // 6291456 B  (end 28704768)
  float* mask2 = (float*)ws;                   // reuses xb space AFTER gemm is done

  const size_t base   = 28704768;
  const size_t o_per  = (size_t)NH * S_LEN * HD * 4;   // 12582912
  const size_t ml_per = (size_t)NH * S_LEN * 2 * 4;    // 393216

  int split = (ws_size >= base + 2 * (o_per + ml_per)) ? 2 : 1;

  k_convert_x<<<dim3(3072), dim3(256), 0, stream>>>(x, xb);
  k_transw<<<dim3(24, 24, 3), dim3(32, 8), 0, stream>>>(Wq, Wk, Wv, wtb);
  k_gemm_qkv<<<dim3(6, 32, 3), dim3(256), 0, stream>>>(xb, wtb, bq, bk, bv, qbb, kbb, vtb);
  k_maskcvt<<<dim3(4), dim3(256), 0, stream>>>(mask, mask2);   // xb dead after gemm

  if (split == 1) {
    k_attn<<<dim3(64, NH, 1), dim3(256), 0, stream>>>(qbb, kbb, vtb, mask2, out, out,
                                                      S_LEN / 64, 1);
  } else {
    float* opart = (float*)(ws + base);
    float* mlb   = (float*)(ws + base + (size_t)split * o_per);
    k_attn<<<dim3(64, NH, split), dim3(256), 0, stream>>>(qbb, kbb, vtb, mask2, opart, mlb,
                                                          S_LEN / (64 * split), 0);
    k_combine<<<dim3(NH * S_LEN * 16 / 256), dim3(256), 0, stream>>>(opart, mlb, out, split);
  }
}

// Round 13
// 184.308 us; speedup vs baseline: 1.5252x; 1.5252x over previous
//
#include <hip/hip_runtime.h>

typedef _Float16 f16;
typedef __attribute__((ext_vector_type(8))) _Float16 half8;
typedef __attribute__((ext_vector_type(4))) _Float16 half4;
typedef __attribute__((ext_vector_type(2))) _Float16 half2v;
typedef __attribute__((ext_vector_type(4))) float f32x4;

#define S_LEN 4096
#define HID   768
#define NH    12
#define HD    64

#define EXP2(x) __builtin_amdgcn_exp2f(x)
#define PKRTZ(a, b) __builtin_bit_cast(half2v, __builtin_amdgcn_cvt_pkrtz((a), (b)))

// ---------------- convert hidden_states f32 -> f16 ----------------
__global__ __launch_bounds__(256) void k_convert_x(const float* __restrict__ x,
                                                   f16* __restrict__ xb) {
  int i = blockIdx.x * 256 + threadIdx.x;
  float4 v = ((const float4*)x)[i];
  half4 h;
  h[0] = (f16)v.x; h[1] = (f16)v.y; h[2] = (f16)v.z; h[3] = (f16)v.w;
  *(half4*)&xb[(size_t)i * 4] = h;
}

// ---------------- mask * log2(e) precompute ----------------
__global__ __launch_bounds__(256) void k_maskcvt(const float* __restrict__ m,
                                                 float* __restrict__ m2) {
  int i = blockIdx.x * 256 + threadIdx.x;
  const float LOG2E = 1.4426950408889634f;
  float4 v = ((const float4*)m)[i];
  ((float4*)m2)[i] = make_float4(v.x * LOG2E, v.y * LOG2E, v.z * LOG2E, v.w * LOG2E);
}

// ---------------- transpose W [K,N] -> wt [N,K], f32 -> f16 ----------------
__global__ __launch_bounds__(256) void k_transw(const float* __restrict__ Wq,
                                                const float* __restrict__ Wk,
                                                const float* __restrict__ Wv,
                                                f16* __restrict__ wtb) {
  __shared__ float tile[32][33];
  const float* W = (blockIdx.z == 0) ? Wq : (blockIdx.z == 1 ? Wk : Wv);
  f16* wt = wtb + (size_t)blockIdx.z * HID * HID;
  int k0 = blockIdx.y * 32, n0 = blockIdx.x * 32;
  int tx = threadIdx.x, ty = threadIdx.y;
  #pragma unroll
  for (int j = ty; j < 32; j += 8)
    tile[j][tx] = W[(size_t)(k0 + j) * HID + n0 + tx];
  __syncthreads();
  #pragma unroll
  for (int j = ty; j < 32; j += 8)
    wt[(size_t)(n0 + j) * HID + k0 + tx] = (f16)tile[tx][j];
}

// ---------------- QKV projection GEMM (m97-style, 128x128 tile) ----------------
__global__ __launch_bounds__(256) void k_gemm_qkv(const f16* __restrict__ xb,
                                                  const f16* __restrict__ wtb,
                                                  const float* __restrict__ bq,
                                                  const float* __restrict__ bk,
                                                  const float* __restrict__ bv,
                                                  f16* __restrict__ qo,
                                                  f16* __restrict__ ko,
                                                  f16* __restrict__ vto) {
  __shared__ __align__(16) f16 As[128 * 32];
  __shared__ __align__(16) f16 Bs[128 * 32];
  const int z = blockIdx.z;
  const f16* wt = wtb + (size_t)z * HID * HID;
  const float* bias = (z == 0) ? bq : (z == 1 ? bk : bv);
  const int brow = blockIdx.y * 128;
  const int bcol = blockIdx.x * 128;
  const int tid = threadIdx.x, wid = tid >> 6, lane = tid & 63;
  const int wr = wid >> 1, wc = wid & 1;
  const int lrow = lane & 15, lk8 = (lane >> 4) * 8;
  const int srow = lane >> 2;
  const int scol = (lane & 3) * 8;

  f32x4 acc[4][4] = {};

  for (int kt = 0; kt < HID; kt += 32) {
    #pragma unroll
    for (int r = 0; r < 2; r++) {
      int row = (wid * 2 + r) * 16 + srow;
      const f16* ga = xb + (size_t)(brow + row) * HID + kt + scol;
      const f16* gb = wt + (size_t)(bcol + row) * HID + kt + scol;
      __builtin_amdgcn_global_load_lds(
          (const __attribute__((address_space(1))) void*)ga,
          (__attribute__((address_space(3))) void*)(As + (wid * 2 + r) * 512),
          16, 0, 0);
      __builtin_amdgcn_global_load_lds(
          (const __attribute__((address_space(1))) void*)gb,
          (__attribute__((address_space(3))) void*)(Bs + (wid * 2 + r) * 512),
          16, 0, 0);
    }
    __syncthreads();

    half8 a[4], b[4];
    #pragma unroll
    for (int m = 0; m < 4; m++)
      a[m] = *(const half8*)&As[(wr * 64 + m * 16 + lrow) * 32 + lk8];
    #pragma unroll
    for (int n = 0; n < 4; n++)
      b[n] = *(const half8*)&Bs[(wc * 64 + n * 16 + lrow) * 32 + lk8];
    #pragma unroll
    for (int m = 0; m < 4; m++)
      #pragma unroll
      for (int n = 0; n < 4; n++)
        acc[m][n] = __builtin_amdgcn_mfma_f32_16x16x32_f16(a[m], b[n], acc[m][n], 0, 0, 0);
    __syncthreads();
  }

  #pragma unroll
  for (int m = 0; m < 4; m++) {
    int row0 = brow + wr * 64 + m * 16 + (lane >> 4) * 4;
    #pragma unroll
    for (int n = 0; n < 4; n++) {
      int col = bcol + wc * 64 + n * 16 + lrow;
      float bsv = bias[col];
      int h = col >> 6, d = col & 63;
      #pragma unroll
      for (int i = 0; i < 4; i++) {
        f16 v = (f16)(acc[m][n][i] + bsv);
        int r2 = row0 + i;
        if (z == 2)      vto[(size_t)(h * HD + d) * S_LEN + r2] = v;
        else if (z == 1) ko[((size_t)h * S_LEN + r2) * HD + d] = v;
        else             qo[((size_t)h * S_LEN + r2) * HD + d] = v;
      }
    }
  }
}

// ---------------- flash attention (KVBLK=32, 6 block-streams/CU) ---------------
// grid (64 q-blocks, 12 heads, split), 256 thr = 4 waves, wave owns 16 q rows.
// KVBLK=32: LDS ~21 KB -> 6 resident blocks/CU (6 independent barrier domains,
// vs 3 in R10 — same 24 waves/CU). K[32][64] and V^T[64][32] staged via
// gload_lds w=16 (double-buffered, pre-swizzled global source; V uses
// sigma(r)=(r&3)^((r>>2)&3) chunk swizzle for its 64B rows). Swapped QK^T,
// per-lane softmax, defer-max T13, P via per-wave LDS (stride 36).
__global__ __launch_bounds__(256) void k_attn(const f16* __restrict__ qb,
                                              const f16* __restrict__ kb,
                                              const f16* __restrict__ vt,
                                              const float* __restrict__ mask2,
                                              float* __restrict__ dsto,
                                              float* __restrict__ ml,
                                              int nkt, int direct) {
  __shared__ __align__(16) f16 Ks[2][32 * 64];   // 4 KB each buf
  __shared__ __align__(16) f16 Vs[2][64 * 32];   // 4 KB each buf
  __shared__ __align__(16) f16 P[4][16 * 36];    // per-wave P tile, stride 36
  const int h = blockIdx.y, z = blockIdx.z;
  const int tid = threadIdx.x, wid = tid >> 6, lane = tid & 63;
  const int lrow = lane & 15, lk8 = (lane >> 4) * 8, g4 = (lane >> 4) * 4;
  const int grp = lane >> 4;
  const int qrow0 = blockIdx.x * 64 + wid * 16;
  const size_t hqk = (size_t)h * (S_LEN * HD);
  const int kt0 = z * nkt * 32;
  f16* Pw = &P[wid][0];
  const float scale2 = 0.125f * 1.4426950408889634f;

  // K staging: 256 thr x 16B = 4 KB; row=tid>>3 (0..31), chunk=tid&7
  const int skrow = tid >> 3, skc = tid & 7;
  const int skcol = ((skc ^ (skrow & 7)) << 3);
  // V staging: row=tid>>2 (0..63, = d), chunk=tid&3; sigma swizzle
  const int svrow = tid >> 2, svc = tid & 3;
  const int svsig = (svrow & 3) ^ ((svrow >> 2) & 3);
  const int svcol = ((svc ^ svsig) << 3);

  const half8 aq0 = *(const half8*)&qb[hqk + (size_t)(qrow0 + lrow) * HD + lk8];
  const half8 aq1 = *(const half8*)&qb[hqk + (size_t)(qrow0 + lrow) * HD + 32 + lk8];

  f32x4 acc[4] = {};
  float mi = -INFINITY, li = 0.f;

  auto stage = [&](int buf, int kt) {
    const f16* gk = kb + hqk + (size_t)(kt + skrow) * HD + skcol;
    const f16* gv = vt + ((size_t)(h * HD + svrow)) * S_LEN + kt + svcol;
    __builtin_amdgcn_global_load_lds(
        (const __attribute__((address_space(1))) void*)gk,
        (__attribute__((address_space(3))) void*)&Ks[buf][tid << 3], 16, 0, 0);
    __builtin_amdgcn_global_load_lds(
        (const __attribute__((address_space(1))) void*)gv,
        (__attribute__((address_space(3))) void*)&Vs[buf][tid << 3], 16, 0, 0);
  };

  stage(0, kt0);
  __syncthreads();

  for (int it = 0; it < nkt; ++it) {
    const int cur = it & 1;
    const int kt = kt0 + it * 32;
    if (it + 1 < nkt) stage(cur ^ 1, kt + 32);   // async prefetch next K/V tile

    // ---- QK^T swapped from LDS: sp[nt][i] = S[k=nt*16+g4+i][q=lrow] ----
    f32x4 sp[2];
    {
      half8 b0[2], b1[2];
      #pragma unroll
      for (int nt = 0; nt < 2; nt++) {
        const int row = nt * 16 + lrow;
        b0[nt] = *(const half8*)&Ks[cur][row * 64 + ((grp ^ (row & 7)) << 3)];
        b1[nt] = *(const half8*)&Ks[cur][row * 64 + (((4 + grp) ^ (row & 7)) << 3)];
      }
      __builtin_amdgcn_s_setprio(1);
      #pragma unroll
      for (int nt = 0; nt < 2; nt++) {
        f32x4 sv = {};
        sv = __builtin_amdgcn_mfma_f32_16x16x32_f16(b0[nt], aq0, sv, 0, 0, 0);
        sv = __builtin_amdgcn_mfma_f32_16x16x32_f16(b1[nt], aq1, sv, 0, 0, 0);
        sp[nt] = sv;
      }
      __builtin_amdgcn_s_setprio(0);
    }
    // ---- scale + pre-scaled mask (log2 domain) ----
    #pragma unroll
    for (int nt = 0; nt < 2; nt++) {
      float4 mk = *(const float4*)&mask2[kt + nt * 16 + g4];
      sp[nt][0] = sp[nt][0] * scale2 + mk.x;
      sp[nt][1] = sp[nt][1] * scale2 + mk.y;
      sp[nt][2] = sp[nt][2] * scale2 + mk.z;
      sp[nt][3] = sp[nt][3] * scale2 + mk.w;
    }
    float mloc = fmaxf(sp[0][0], sp[0][1]);
    mloc = fmaxf(fmaxf(mloc, sp[0][2]), sp[0][3]);
    mloc = fmaxf(fmaxf(mloc, sp[1][0]), sp[1][1]);
    mloc = fmaxf(fmaxf(mloc, sp[1][2]), sp[1][3]);
    mloc = fmaxf(mloc, __shfl_xor(mloc, 16, 64));
    mloc = fmaxf(mloc, __shfl_xor(mloc, 32, 64));

    // ---- defer-max (T13, THR=8 -> P <= 256, f16-safe) ----
    float al = 1.f;
    if (!__all(mloc <= mi + 8.f)) {
      const float mn = fmaxf(mi, mloc);
      al = EXP2(mi - mn);
      mi = mn;
      #pragma unroll
      for (int nd = 0; nd < 4; nd++) {
        acc[nd][0] *= al; acc[nd][1] *= al; acc[nd][2] *= al; acc[nd][3] *= al;
      }
    }
    float rs = 0.f;
    #pragma unroll
    for (int nt = 0; nt < 2; nt++)
      #pragma unroll
      for (int i = 0; i < 4; i++) {
        sp[nt][i] = EXP2(sp[nt][i] - mi);
        rs += sp[nt][i];
      }
    rs += __shfl_xor(rs, 16, 64);
    rs += __shfl_xor(rs, 32, 64);
    li = li * al + rs;

    // ---- P -> LDS row-major [q=lrow][k 32], packed cvt ----
    #pragma unroll
    for (int nt = 0; nt < 2; nt++) {
      half2v lo = PKRTZ(sp[nt][0], sp[nt][1]);
      half2v hi = PKRTZ(sp[nt][2], sp[nt][3]);
      half4 h4;
      h4[0] = lo[0]; h4[1] = lo[1]; h4[2] = hi[0]; h4[3] = hi[1];
      *(half4*)&Pw[lrow * 36 + nt * 16 + g4] = h4;
    }
    // ---- PV from LDS: acc[nd] = O^T[d][q] += V^T[d][k 32] P^T[k][q] ----
    {
      half8 bp = *(const half8*)&Pw[lrow * 36 + lk8];
      __builtin_amdgcn_s_setprio(1);
      #pragma unroll
      for (int nd = 0; nd < 4; nd++) {
        const int vr = nd * 16 + lrow;
        const int sig = (vr & 3) ^ ((vr >> 2) & 3);
        half8 av = *(const half8*)&Vs[cur][vr * 32 + ((grp ^ sig) << 3)];
        acc[nd] = __builtin_amdgcn_mfma_f32_16x16x32_f16(av, bp, acc[nd], 0, 0, 0);
      }
      __builtin_amdgcn_s_setprio(0);
    }
    __syncthreads();   // staged tiles landed; release cur buf
  }

  const float inv = (li > 0.f) ? (1.f / li) : 0.f;
  if (direct) {
    #pragma unroll
    for (int nd = 0; nd < 4; nd++) {
      float4 o = make_float4(acc[nd][0] * inv, acc[nd][1] * inv,
                             acc[nd][2] * inv, acc[nd][3] * inv);
      *(float4*)&dsto[(size_t)(qrow0 + lrow) * HID + h * HD + nd * 16 + g4] = o;
    }
  } else {
    const size_t rbase = ((size_t)z * NH + h) * S_LEN + qrow0 + lrow;
    #pragma unroll
    for (int nd = 0; nd < 4; nd++) {
      float4 o = make_float4(acc[nd][0] * inv, acc[nd][1] * inv,
                             acc[nd][2] * inv, acc[nd][3] * inv);
      *(float4*)&dsto[rbase * HD + nd * 16 + g4] = o;
    }
    if (lane < 16) {
      ml[rbase * 2]     = mi;   // log2-domain running max
      ml[rbase * 2 + 1] = li;
    }
  }
}

// ---------------- split-KV combine (log2-domain weights) ----------------
__global__ __launch_bounds__(256) void k_combine(const float* __restrict__ opart,
                                                 const float* __restrict__ ml,
                                                 float* __restrict__ out, int split) {
  const int gid = blockIdx.x * 256 + threadIdx.x;   // NH*S*16 threads
  const int row = gid >> 4;                          // h*S + q
  const int d0 = (gid & 15) << 2;
  const int h = row >> 12, q = row & (S_LEN - 1);
  float M = -INFINITY;
  for (int zz = 0; zz < split; zz++)
    M = fmaxf(M, ml[((size_t)zz * NH * S_LEN + row) * 2]);
  float wsum = 0.f;
  float o0 = 0.f, o1 = 0.f, o2 = 0.f, o3 = 0.f;
  for (int zz = 0; zz < split; zz++) {
    const size_t r = (size_t)zz * NH * S_LEN + row;
    float m = ml[r * 2], l = ml[r * 2 + 1];
    if (l > 0.f) {
      float w = l * EXP2(m - M);
      float4 v = *(const float4*)&opart[r * HD + d0];
      wsum += w;
      o0 += w * v.x; o1 += w * v.y; o2 += w * v.z; o3 += w * v.w;
    }
  }
  const float inv = (wsum > 0.f) ? (1.f / wsum) : 0.f;
  *(float4*)&out[(size_t)q * HID + h * HD + d0] =
      make_float4(o0 * inv, o1 * inv, o2 * inv, o3 * inv);
}

extern "C" void kernel_launch(void* const* d_in, const int* in_sizes, int n_in,
                              void* d_out, int out_size, void* d_ws, size_t ws_size,
                              hipStream_t stream) {
  const float* x    = (const float*)d_in[0];
  const float* mask = (const float*)d_in[1];
  const float* Wq   = (const float*)d_in[2];
  const float* bq   = (const float*)d_in[3];
  const float* Wk   = (const float*)d_in[4];
  const float* bk   = (const float*)d_in[5];
  const float* Wv   = (const float*)d_in[6];
  const float* bv   = (const float*)d_in[7];
  float* out = (float*)d_out;

  char* ws = (char*)d_ws;
  f16* xb  = (f16*)(ws);                       // 4096*768*2       = 6291456 B
  f16* wtb = (f16*)(ws + 6291456);             // 3*768*768*2      = 3538944 B
  f16* qbb = (f16*)(ws + 9830400);             // 12*4096*64*2     = 6291456 B
  f16* kbb = (f16*)(ws + 16121856);            // 6291456 B
  f16* vtb = (f16*)(ws + 22413312);            // 6291456 B  (end 28704768)
  float* mask2 = (float*)ws;                   // reuses xb space AFTER gemm is done

  const size_t base   = 28704768;
  const size_t o_per  = (size_t)NH * S_LEN * HD * 4;   // 12582912
  const size_t ml_per = (size_t)NH * S_LEN * 2 * 4;    // 393216

  int split = (ws_size >= base + 2 * (o_per + ml_per)) ? 2 : 1;

  k_convert_x<<<dim3(3072), dim3(256), 0, stream>>>(x, xb);
  k_transw<<<dim3(24, 24, 3), dim3(32, 8), 0, stream>>>(Wq, Wk, Wv, wtb);
  k_gemm_qkv<<<dim3(6, 32, 3), dim3(256), 0, stream>>>(xb, wtb, bq, bk, bv, qbb, kbb, vtb);
  k_maskcvt<<<dim3(4), dim3(256), 0, stream>>>(mask, mask2);   // xb dead after gemm

  if (split == 1) {
    k_attn<<<dim3(64, NH, 1), dim3(256), 0, stream>>>(qbb, kbb, vtb, mask2, out, out,
                                                      S_LEN / 32, 1);
  } else {
    float* opart = (float*)(ws + base);
    float* mlb   = (float*)(ws + base + (size_t)split * o_per);
    k_attn<<<dim3(64, NH, split), dim3(256), 0, stream>>>(qbb, kbb, vtb, mask2, opart, mlb,
                                                          S_LEN / (32 * split), 0);
    k_combine<<<dim3(NH * S_LEN * 16 / 256), dim3(256), 0, stream>>>(opart, mlb, out, split);
  }
}

// Round 14
// 176.954 us; speedup vs baseline: 1.5886x; 1.0416x over previous
//
#include <hip/hip_runtime.h>

typedef _Float16 f16;
typedef __attribute__((ext_vector_type(8))) _Float16 half8;
typedef __attribute__((ext_vector_type(4))) _Float16 half4;
typedef __attribute__((ext_vector_type(2))) _Float16 half2v;
typedef __attribute__((ext_vector_type(4))) float f32x4;

#define S_LEN 4096
#define HID   768
#define NH    12
#define HD    64

#define EXP2(x) __builtin_amdgcn_exp2f(x)
#define PKRTZ(a, b) __builtin_bit_cast(half2v, __builtin_amdgcn_cvt_pkrtz((a), (b)))

// ---------------- convert hidden_states f32 -> f16 ----------------
__global__ __launch_bounds__(256) void k_convert_x(const float* __restrict__ x,
                                                   f16* __restrict__ xb) {
  int i = blockIdx.x * 256 + threadIdx.x;
  float4 v = ((const float4*)x)[i];
  half4 h;
  h[0] = (f16)v.x; h[1] = (f16)v.y; h[2] = (f16)v.z; h[3] = (f16)v.w;
  *(half4*)&xb[(size_t)i * 4] = h;
}

// ---------------- mask * log2(e) precompute ----------------
__global__ __launch_bounds__(256) void k_maskcvt(const float* __restrict__ m,
                                                 float* __restrict__ m2) {
  int i = blockIdx.x * 256 + threadIdx.x;
  const float LOG2E = 1.4426950408889634f;
  float4 v = ((const float4*)m)[i];
  ((float4*)m2)[i] = make_float4(v.x * LOG2E, v.y * LOG2E, v.z * LOG2E, v.w * LOG2E);
}

// ---------------- transpose W [K,N] -> wt [N,K], f32 -> f16 ----------------
__global__ __launch_bounds__(256) void k_transw(const float* __restrict__ Wq,
                                                const float* __restrict__ Wk,
                                                const float* __restrict__ Wv,
                                                f16* __restrict__ wtb) {
  __shared__ float tile[32][33];
  const float* W = (blockIdx.z == 0) ? Wq : (blockIdx.z == 1 ? Wk : Wv);
  f16* wt = wtb + (size_t)blockIdx.z * HID * HID;
  int k0 = blockIdx.y * 32, n0 = blockIdx.x * 32;
  int tx = threadIdx.x, ty = threadIdx.y;
  #pragma unroll
  for (int j = ty; j < 32; j += 8)
    tile[j][tx] = W[(size_t)(k0 + j) * HID + n0 + tx];
  __syncthreads();
  #pragma unroll
  for (int j = ty; j < 32; j += 8)
    wt[(size_t)(n0 + j) * HID + k0 + tx] = (f16)tile[tx][j];
}

// ---------------- QKV projection GEMM (m97-style, 128x128 tile) ----------------
__global__ __launch_bounds__(256) void k_gemm_qkv(const f16* __restrict__ xb,
                                                  const f16* __restrict__ wtb,
                                                  const float* __restrict__ bq,
                                                  const float* __restrict__ bk,
                                                  const float* __restrict__ bv,
                                                  f16* __restrict__ qo,
                                                  f16* __restrict__ ko,
                                                  f16* __restrict__ vto) {
  __shared__ __align__(16) f16 As[128 * 32];
  __shared__ __align__(16) f16 Bs[128 * 32];
  const int z = blockIdx.z;
  const f16* wt = wtb + (size_t)z * HID * HID;
  const float* bias = (z == 0) ? bq : (z == 1 ? bk : bv);
  const int brow = blockIdx.y * 128;
  const int bcol = blockIdx.x * 128;
  const int tid = threadIdx.x, wid = tid >> 6, lane = tid & 63;
  const int wr = wid >> 1, wc = wid & 1;
  const int lrow = lane & 15, lk8 = (lane >> 4) * 8;
  const int srow = lane >> 2;
  const int scol = (lane & 3) * 8;

  f32x4 acc[4][4] = {};

  for (int kt = 0; kt < HID; kt += 32) {
    #pragma unroll
    for (int r = 0; r < 2; r++) {
      int row = (wid * 2 + r) * 16 + srow;
      const f16* ga = xb + (size_t)(brow + row) * HID + kt + scol;
      const f16* gb = wt + (size_t)(bcol + row) * HID + kt + scol;
      __builtin_amdgcn_global_load_lds(
          (const __attribute__((address_space(1))) void*)ga,
          (__attribute__((address_space(3))) void*)(As + (wid * 2 + r) * 512),
          16, 0, 0);
      __builtin_amdgcn_global_load_lds(
          (const __attribute__((address_space(1))) void*)gb,
          (__attribute__((address_space(3))) void*)(Bs + (wid * 2 + r) * 512),
          16, 0, 0);
    }
    __syncthreads();

    half8 a[4], b[4];
    #pragma unroll
    for (int m = 0; m < 4; m++)
      a[m] = *(const half8*)&As[(wr * 64 + m * 16 + lrow) * 32 + lk8];
    #pragma unroll
    for (int n = 0; n < 4; n++)
      b[n] = *(const half8*)&Bs[(wc * 64 + n * 16 + lrow) * 32 + lk8];
    #pragma unroll
    for (int m = 0; m < 4; m++)
      #pragma unroll
      for (int n = 0; n < 4; n++)
        acc[m][n] = __builtin_amdgcn_mfma_f32_16x16x32_f16(a[m], b[n], acc[m][n], 0, 0, 0);
    __syncthreads();
  }

  #pragma unroll
  for (int m = 0; m < 4; m++) {
    int row0 = brow + wr * 64 + m * 16 + (lane >> 4) * 4;
    #pragma unroll
    for (int n = 0; n < 4; n++) {
      int col = bcol + wc * 64 + n * 16 + lrow;
      float bsv = bias[col];
      int h = col >> 6, d = col & 63;
      #pragma unroll
      for (int i = 0; i < 4; i++) {
        f16 v = (f16)(acc[m][n][i] + bsv);
        int r2 = row0 + i;
        if (z == 2)      vto[(size_t)(h * HD + d) * S_LEN + r2] = v;
        else if (z == 1) ko[((size_t)h * S_LEN + r2) * HD + d] = v;
        else             qo[((size_t)h * S_LEN + r2) * HD + d] = v;
      }
    }
  }
}

// ---------------- flash attention (32 q/wave @16x16: K/V-frag reuse) -----------
// grid (32 q-blocks, 12 heads, split), 256 thr = 4 waves, wave owns 32 q rows
// (two 16-row halves H=0,1). K and V frags are loaded from LDS ONCE per iter
// and reused for both halves -> LDS instrs per unit work cut ~40% (the R10
// binding pipe at ~73% busy). KVBLK=64, K/V dbuf staged (gload_lds w=16,
// XOR-swizzled source). Swapped QK^T, per-lane softmax, defer-max T13.
__global__ __launch_bounds__(256) void k_attn(const f16* __restrict__ qb,
                                              const f16* __restrict__ kb,
                                              const f16* __restrict__ vt,
                                              const float* __restrict__ mask2,
                                              float* __restrict__ dsto,
                                              float* __restrict__ ml,
                                              int nkt, int direct) {
  __shared__ __align__(16) f16 Ks[2][64 * 64];   // 8 KB each buf
  __shared__ __align__(16) f16 Vs[2][64 * 64];
  __shared__ __align__(16) f16 P[4][32 * 72];    // per-wave P tile, 32 rows
  const int h = blockIdx.y, z = blockIdx.z;
  const int tid = threadIdx.x, wid = tid >> 6, lane = tid & 63;
  const int lrow = lane & 15, lk8 = (lane >> 4) * 8, g4 = (lane >> 4) * 4;
  const int grp = lane >> 4;
  const int qrow0 = blockIdx.x * 128 + wid * 32;
  const size_t hqk = (size_t)h * (S_LEN * HD);
  const int kt0 = z * nkt * 64;
  f16* Pw = &P[wid][0];
  const float scale2 = 0.125f * 1.4426950408889634f;

  // staging geometry: 2 rounds x 256 threads x 16B per matrix (8 KB tile)
  const int srow = tid >> 3;
  const int sc   = tid & 7;

  half8 aq[2][2];
  #pragma unroll
  for (int H = 0; H < 2; H++) {
    aq[H][0] = *(const half8*)&qb[hqk + (size_t)(qrow0 + H * 16 + lrow) * HD + lk8];
    aq[H][1] = *(const half8*)&qb[hqk + (size_t)(qrow0 + H * 16 + lrow) * HD + 32 + lk8];
  }

  f32x4 acc[2][4] = {};
  float mi[2] = {-INFINITY, -INFINITY}, li[2] = {0.f, 0.f};

  auto stage = [&](int buf, int kt) {
    #pragma unroll
    for (int r = 0; r < 2; r++) {
      const int row = r * 32 + srow;
      const int scol = ((sc ^ (row & 7)) << 3);
      const f16* gk = kb + hqk + (size_t)(kt + row) * HD + scol;
      const f16* gv = vt + ((size_t)(h * HD + row)) * S_LEN + kt + scol;
      __builtin_amdgcn_global_load_lds(
          (const __attribute__((address_space(1))) void*)gk,
          (__attribute__((address_space(3))) void*)&Ks[buf][r * 2048 + (tid << 3)],
          16, 0, 0);
      __builtin_amdgcn_global_load_lds(
          (const __attribute__((address_space(1))) void*)gv,
          (__attribute__((address_space(3))) void*)&Vs[buf][r * 2048 + (tid << 3)],
          16, 0, 0);
    }
  };

  stage(0, kt0);
  __syncthreads();

  for (int it = 0; it < nkt; ++it) {
    const int cur = it & 1;
    const int kt = kt0 + it * 64;
    if (it + 1 < nkt) stage(cur ^ 1, kt + 64);   // async prefetch next K/V tile

    // ---- K frags ONCE, QK^T for both halves ----
    f32x4 sp[2][4];
    {
      half8 b0[4], b1[4];
      #pragma unroll
      for (int nt = 0; nt < 4; nt++) {
        const int row = nt * 16 + lrow;
        b0[nt] = *(const half8*)&Ks[cur][row * 64 + ((grp ^ (row & 7)) << 3)];
        b1[nt] = *(const half8*)&Ks[cur][row * 64 + (((4 + grp) ^ (row & 7)) << 3)];
      }
      __builtin_amdgcn_s_setprio(1);
      #pragma unroll
      for (int H = 0; H < 2; H++)
        #pragma unroll
        for (int nt = 0; nt < 4; nt++) {
          f32x4 sv = {};
          sv = __builtin_amdgcn_mfma_f32_16x16x32_f16(b0[nt], aq[H][0], sv, 0, 0, 0);
          sv = __builtin_amdgcn_mfma_f32_16x16x32_f16(b1[nt], aq[H][1], sv, 0, 0, 0);
          sp[H][nt] = sv;
        }
      __builtin_amdgcn_s_setprio(0);
    }

    // ---- mask loads once (mask depends only on k) ----
    float4 mk[4];
    #pragma unroll
    for (int nt = 0; nt < 4; nt++)
      mk[nt] = *(const float4*)&mask2[kt + nt * 16 + g4];

    // ---- softmax per half (independent -> ILP) ----
    #pragma unroll
    for (int H = 0; H < 2; H++) {
      #pragma unroll
      for (int nt = 0; nt < 4; nt++) {
        sp[H][nt][0] = sp[H][nt][0] * scale2 + mk[nt].x;
        sp[H][nt][1] = sp[H][nt][1] * scale2 + mk[nt].y;
        sp[H][nt][2] = sp[H][nt][2] * scale2 + mk[nt].z;
        sp[H][nt][3] = sp[H][nt][3] * scale2 + mk[nt].w;
      }
      float mloc = fmaxf(sp[H][0][0], sp[H][0][1]);
      mloc = fmaxf(fmaxf(mloc, sp[H][0][2]), sp[H][0][3]);
      mloc = fmaxf(fmaxf(mloc, sp[H][1][0]), sp[H][1][1]);
      mloc = fmaxf(fmaxf(mloc, sp[H][1][2]), sp[H][1][3]);
      mloc = fmaxf(fmaxf(mloc, sp[H][2][0]), sp[H][2][1]);
      mloc = fmaxf(fmaxf(mloc, sp[H][2][2]), sp[H][2][3]);
      mloc = fmaxf(fmaxf(mloc, sp[H][3][0]), sp[H][3][1]);
      mloc = fmaxf(fmaxf(mloc, sp[H][3][2]), sp[H][3][3]);
      mloc = fmaxf(mloc, __shfl_xor(mloc, 16, 64));
      mloc = fmaxf(mloc, __shfl_xor(mloc, 32, 64));

      float al = 1.f;
      if (!__all(mloc <= mi[H] + 8.f)) {
        const float mn = fmaxf(mi[H], mloc);
        al = EXP2(mi[H] - mn);
        mi[H] = mn;
        #pragma unroll
        for (int nd = 0; nd < 4; nd++) {
          acc[H][nd][0] *= al; acc[H][nd][1] *= al;
          acc[H][nd][2] *= al; acc[H][nd][3] *= al;
        }
      }
      float rs = 0.f;
      #pragma unroll
      for (int nt = 0; nt < 4; nt++)
        #pragma unroll
        for (int i = 0; i < 4; i++) {
          sp[H][nt][i] = EXP2(sp[H][nt][i] - mi[H]);
          rs += sp[H][nt][i];
        }
      rs += __shfl_xor(rs, 16, 64);
      rs += __shfl_xor(rs, 32, 64);
      li[H] = li[H] * al + rs;

      // P rows: H*16 + lrow
      #pragma unroll
      for (int nt = 0; nt < 4; nt++) {
        half2v lo = PKRTZ(sp[H][nt][0], sp[H][nt][1]);
        half2v hi = PKRTZ(sp[H][nt][2], sp[H][nt][3]);
        half4 h4;
        h4[0] = lo[0]; h4[1] = lo[1]; h4[2] = hi[0]; h4[3] = hi[1];
        *(half4*)&Pw[(H * 16 + lrow) * 72 + nt * 16 + g4] = h4;
      }
    }

    // ---- PV: V frags ONCE, both halves ----
    #pragma unroll
    for (int k2 = 0; k2 < 2; k2++) {
      half8 bp0 = *(const half8*)&Pw[lrow * 72 + k2 * 32 + lk8];
      half8 bp1 = *(const half8*)&Pw[(16 + lrow) * 72 + k2 * 32 + lk8];
      __builtin_amdgcn_s_setprio(1);
      #pragma unroll
      for (int nd = 0; nd < 4; nd++) {
        const int vr = nd * 16 + lrow;
        const int xc = (((k2 * 4 + grp) ^ (vr & 7)) << 3);
        half8 av = *(const half8*)&Vs[cur][vr * 64 + xc];
        acc[0][nd] = __builtin_amdgcn_mfma_f32_16x16x32_f16(av, bp0, acc[0][nd], 0, 0, 0);
        acc[1][nd] = __builtin_amdgcn_mfma_f32_16x16x32_f16(av, bp1, acc[1][nd], 0, 0, 0);
      }
      __builtin_amdgcn_s_setprio(0);
    }
    __syncthreads();   // staged tiles landed; release cur buf
  }

  #pragma unroll
  for (int H = 0; H < 2; H++) {
    const float inv = (li[H] > 0.f) ? (1.f / li[H]) : 0.f;
    if (direct) {
      #pragma unroll
      for (int nd = 0; nd < 4; nd++) {
        float4 o = make_float4(acc[H][nd][0] * inv, acc[H][nd][1] * inv,
                               acc[H][nd][2] * inv, acc[H][nd][3] * inv);
        *(float4*)&dsto[(size_t)(qrow0 + H * 16 + lrow) * HID + h * HD + nd * 16 + g4] = o;
      }
    } else {
      const size_t rbase = ((size_t)z * NH + h) * S_LEN + qrow0 + H * 16 + lrow;
      #pragma unroll
      for (int nd = 0; nd < 4; nd++) {
        float4 o = make_float4(acc[H][nd][0] * inv, acc[H][nd][1] * inv,
                               acc[H][nd][2] * inv, acc[H][nd][3] * inv);
        *(float4*)&dsto[rbase * HD + nd * 16 + g4] = o;
      }
      if (lane < 16) {
        ml[rbase * 2]     = mi[H];
        ml[rbase * 2 + 1] = li[H];
      }
    }
  }
}

// ---------------- split-KV combine (log2-domain weights) ----------------
__global__ __launch_bounds__(256) void k_combine(const float* __restrict__ opart,
                                                 const float* __restrict__ ml,
                                                 float* __restrict__ out, int split) {
  const int gid = blockIdx.x * 256 + threadIdx.x;   // NH*S*16 threads
  const int row = gid >> 4;                          // h*S + q
  const int d0 = (gid & 15) << 2;
  const int h = row >> 12, q = row & (S_LEN - 1);
  float M = -INFINITY;
  for (int zz = 0; zz < split; zz++)
    M = fmaxf(M, ml[((size_t)zz * NH * S_LEN + row) * 2]);
  float wsum = 0.f;
  float o0 = 0.f, o1 = 0.f, o2 = 0.f, o3 = 0.f;
  for (int zz = 0; zz < split; zz++) {
    const size_t r = (size_t)zz * NH * S_LEN + row;
    float m = ml[r * 2], l = ml[r * 2 + 1];
    if (l > 0.f) {
      float w = l * EXP2(m - M);
      float4 v = *(const float4*)&opart[r * HD + d0];
      wsum += w;
      o0 += w * v.x; o1 += w * v.y; o2 += w * v.z; o3 += w * v.w;
    }
  }
  const float inv = (wsum > 0.f) ? (1.f / wsum) : 0.f;
  *(float4*)&out[(size_t)q * HID + h * HD + d0] =
      make_float4(o0 * inv, o1 * inv, o2 * inv, o3 * inv);
}

extern "C" void kernel_launch(void* const* d_in, const int* in_sizes, int n_in,
                              void* d_out, int out_size, void* d_ws, size_t ws_size,
                              hipStream_t stream) {
  const float* x    = (const float*)d_in[0];
  const float* mask = (const float*)d_in[1];
  const float* Wq   = (const float*)d_in[2];
  const float* bq   = (const float*)d_in[3];
  const float* Wk   = (const float*)d_in[4];
  const float* bk   = (const float*)d_in[5];
  const float* Wv   = (const float*)d_in[6];
  const float* bv   = (const float*)d_in[7];
  float* out = (float*)d_out;

  char* ws = (char*)d_ws;
  f16* xb  = (f16*)(ws);                       // 4096*768*2       = 6291456 B
  f16* wtb = (f16*)(ws + 6291456);             // 3*768*768*2      = 3538944 B
  f16* qbb = (f16*)(ws + 9830400);             // 12*4096*64*2     = 6291456 B
  f16* kbb = (f16*)(ws + 16121856);            // 6291456 B
  f16* vtb = (f16*)(ws + 22413312);            // 6291456 B  (end 28704768)
  float* mask2 = (float*)ws;                   // reuses xb space AFTER gemm is done

  const size_t base   = 28704768;
  const size_t o_per  = (size_t)NH * S_LEN * HD * 4;   // 12582912
  const size_t ml_per = (size_t)NH * S_LEN * 2 * 4;    // 393216

  int split = (ws_size >= base + 2 * (o_per + ml_per)) ? 2 : 1;

  k_convert_x<<<dim3(3072), dim3(256), 0, stream>>>(x, xb);
  k_transw<<<dim3(24, 24, 3), dim3(32, 8), 0, stream>>>(Wq, Wk, Wv, wtb);
  k_gemm_qkv<<<dim3(6, 32, 3), dim3(256), 0, stream>>>(xb, wtb, bq, bk, bv, qbb, kbb, vtb);
  k_maskcvt<<<dim3(4), dim3(256), 0, stream>>>(mask, mask2);   // xb dead after gemm

  if (split == 1) {
    k_attn<<<dim3(32, NH, 1), dim3(256), 0, stream>>>(qbb, kbb, vtb, mask2, out, out,
                                                      S_LEN / 64, 1);
  } else {
    float* opart = (float*)(ws + base);
    float* mlb   = (float*)(ws + base + (size_t)split * o_per);
    k_attn<<<dim3(32, NH, split), dim3(256), 0, stream>>>(qbb, kbb, vtb, mask2, opart, mlb,
                                                          S_LEN / (64 * split), 0);
    k_combine<<<dim3(NH * S_LEN * 16 / 256), dim3(256), 0, stream>>>(opart, mlb, out, split);
  }
}